// Round 1
// baseline (612.830 us; speedup 1.0000x reference)
//
#include <hip/hip_runtime.h>

#define B_  32
#define C_  128
#define CS  64
#define H_  64
#define W_  64
#define HW  (H_*W_)

__device__ __forceinline__ float silu_f(float v) { return v / (1.f + __expf(-v)); }

__device__ __forceinline__ void get_coeffs(const float* __restrict__ wts,
                                           const int* __restrict__ idxs, int b,
                                           float& c0, float& c1, float& c2, float& cid) {
    int   i0 = idxs[b*2+0], i1 = idxs[b*2+1];
    float w0 = wts[b*2+0],  w1 = wts[b*2+1];
    c0  = (i0==0?w0:0.f)   + (i1==0?w1:0.f);
    c1  = (i0==1?w0:0.f)   + (i1==1?w1:0.f);
    c2  = (i0==2?w0:0.f)   + (i1==2?w1:0.f);
    cid = (i0==3?0.1f:0.f) + (i1==3?0.1f:0.f);
}

// ---------------- Kernel A: e0 = silu(bn(conv3x3(x_rgb))) ; out = c0*e0 + cid*x ----
// grid (64, B): blockIdx.x = cg(16)*4 + rg(4). block 256.
// Each thread: 8 couts x 4 w-pixels.
__global__ __launch_bounds__(256) void k_e0_id(
    const float* __restrict__ x, const float* __restrict__ wts, const int* __restrict__ idxs,
    const float* __restrict__ e0w, const float* __restrict__ gg, const float* __restrict__ bb,
    const float* __restrict__ mm, const float* __restrict__ vv, float* __restrict__ out)
{
    const int b  = blockIdx.y;
    const int cg = blockIdx.x >> 2;   // 0..15
    const int rg = blockIdx.x & 3;    // 0..3
    const int t  = threadIdx.x;
    const int row = rg*16 + (t >> 4);
    const int w0  = (t & 15) * 4;

    float c0, c1, c2, cid;
    get_coeffs(wts, idxs, b, c0, c1, c2, cid);

    __shared__ float wlds[8*576];
    __shared__ float s_s[8], s_t[8];

    if (c0 == 0.f) {   // uniform per block: only identity contribution
        #pragma unroll
        for (int i = 0; i < 8; ++i) {
            int co = cg*8 + i;
            size_t base = ((size_t)(b*C_ + co))*HW + row*W_ + w0;
            float4 xv = *(const float4*)(x + base);
            float4 o; o.x = cid*xv.x; o.y = cid*xv.y; o.z = cid*xv.z; o.w = cid*xv.w;
            *(float4*)(out + base) = o;
        }
        return;
    }

    for (int i = t; i < 8*576; i += 256) {
        int co_l = i / 576, rest = i % 576;
        wlds[i] = e0w[(size_t)(cg*8 + co_l)*576 + rest];
    }
    if (t < 8) {
        int co = cg*8 + t;
        float s = gg[co] * rsqrtf(vv[co] + 1e-5f);
        s_s[t] = s; s_t[t] = bb[co] - mm[co]*s;
    }
    __syncthreads();

    float acc[8][4];
    #pragma unroll
    for (int i = 0; i < 8; ++i)
        #pragma unroll
        for (int p = 0; p < 4; ++p) acc[i][p] = 0.f;

    const float* xb = x + (size_t)b*C_*HW;   // x_rgb = channels 0..63
    for (int ci = 0; ci < 64; ++ci) {
        const float* xc = xb + ci*HW;
        #pragma unroll
        for (int dh = 0; dh < 3; ++dh) {
            int hh = row + dh - 1;
            float rbuf[6];
            if (hh >= 0 && hh < H_) {
                const float* xr = xc + hh*W_;
                #pragma unroll
                for (int i = 0; i < 6; ++i) {
                    int wloc = w0 - 1 + i;
                    rbuf[i] = (wloc >= 0 && wloc < W_) ? xr[wloc] : 0.f;
                }
            } else {
                #pragma unroll
                for (int i = 0; i < 6; ++i) rbuf[i] = 0.f;
            }
            #pragma unroll
            for (int co = 0; co < 8; ++co) {
                const float* wp = &wlds[co*576 + ci*9 + dh*3];
                float wa = wp[0], wb = wp[1], wc = wp[2];
                #pragma unroll
                for (int p = 0; p < 4; ++p)
                    acc[co][p] += rbuf[p]*wa + rbuf[p+1]*wb + rbuf[p+2]*wc;
            }
        }
    }

    #pragma unroll
    for (int i = 0; i < 8; ++i) {
        int co = cg*8 + i;
        size_t base = ((size_t)(b*C_ + co))*HW + row*W_ + w0;
        float4 xv = *(const float4*)(x + base);
        float s = s_s[i], tt = s_t[i];
        float4 o;
        float v0 = c0*silu_f(acc[i][0]*s + tt);
        float v1 = c0*silu_f(acc[i][1]*s + tt);
        float v2 = c0*silu_f(acc[i][2]*s + tt);
        float v3 = c0*silu_f(acc[i][3]*s + tt);
        o.x = v0 + cid*xv.x; o.y = v1 + cid*xv.y; o.z = v2 + cid*xv.z; o.w = v3 + cid*xv.w;
        *(float4*)(out + base) = o;
    }
}

// ---------------- Kernel B1: tmp = dwconv5x5(x_ir)  (no bn) --------------------
// grid (64, B): one (b, channel) plane per block.
__global__ __launch_bounds__(256) void k_e1_dw(
    const float* __restrict__ x, const float* __restrict__ wts, const int* __restrict__ idxs,
    const float* __restrict__ dww, float* __restrict__ tmp)
{
    const int b = blockIdx.y;
    const int c = blockIdx.x;   // 0..63
    const int t = threadIdx.x;

    float c0, c1, c2, cid;
    get_coeffs(wts, idxs, b, c0, c1, c2, cid);
    if (c1 == 0.f) return;

    __shared__ float wl[25];
    if (t < 25) wl[t] = dww[c*25 + t];
    __syncthreads();

    const float* xc = x + ((size_t)(b*C_ + CS + c))*HW;
    float* tc = tmp + ((size_t)(b*CS + c))*HW;
    for (int p = t; p < HW; p += 256) {
        int h = p >> 6, w = p & 63;
        float a = 0.f;
        #pragma unroll
        for (int kh = 0; kh < 5; ++kh) {
            int hh = h + kh - 2;
            if (hh < 0 || hh >= H_) continue;
            #pragma unroll
            for (int kw = 0; kw < 5; ++kw) {
                int ww = w + kw - 2;
                if (ww < 0 || ww >= W_) continue;
                a += xc[hh*W_ + ww] * wl[kh*5 + kw];
            }
        }
        tc[p] = a;
    }
}

// ---------------- Kernel B2: out += c1 * silu(bn(pw1x1(tmp))) -------------------
// grid (256, B): blockIdx.x = cg(16)*16 + pixel-chunk(16). block 256 (1 pixel/thread, 8 couts).
__global__ __launch_bounds__(256) void k_e1_pw(
    const float* __restrict__ tmp, const float* __restrict__ wts, const int* __restrict__ idxs,
    const float* __restrict__ pww, const float* __restrict__ gg, const float* __restrict__ bb,
    const float* __restrict__ mm, const float* __restrict__ vv, float* __restrict__ out)
{
    const int b  = blockIdx.y;
    const int cg = blockIdx.x >> 4;   // 0..15
    const int pc = blockIdx.x & 15;   // 0..15
    const int t  = threadIdx.x;

    float c0, c1, c2, cid;
    get_coeffs(wts, idxs, b, c0, c1, c2, cid);
    if (c1 == 0.f) return;

    __shared__ float wl[8*64];
    __shared__ float s_s[8], s_t[8];
    for (int i = t; i < 8*64; i += 256) {
        int co_l = i >> 6, ci = i & 63;
        wl[i] = pww[(size_t)(cg*8 + co_l)*64 + ci];
    }
    if (t < 8) {
        int co = cg*8 + t;
        float s = gg[co] * rsqrtf(vv[co] + 1e-5f);
        s_s[t] = s; s_t[t] = bb[co] - mm[co]*s;
    }
    __syncthreads();

    const int pix = pc*256 + t;
    const float* tb = tmp + (size_t)b*CS*HW + pix;
    float acc[8];
    #pragma unroll
    for (int i = 0; i < 8; ++i) acc[i] = 0.f;

    for (int ci = 0; ci < 64; ++ci) {
        float tv = tb[(size_t)ci*HW];
        #pragma unroll
        for (int co = 0; co < 8; ++co) acc[co] += tv * wl[co*64 + ci];
    }

    #pragma unroll
    for (int i = 0; i < 8; ++i) {
        int co = cg*8 + i;
        size_t o = ((size_t)(b*C_ + co))*HW + pix;
        float val = silu_f(acc[i]*s_s[i] + s_t[i]);
        out[o] += c1 * val;
    }
}

// ---------------- Kernel C: g1 = silu(bn(conv3x3(x,128->64))); out[:, :64] += c2*g1
// grid (32, B): blockIdx.x = cg(8)*4 + rg(4). block 256. 8 couts x 4 pixels / thread.
__global__ __launch_bounds__(256) void k_e2a(
    const float* __restrict__ x, const float* __restrict__ wts, const int* __restrict__ idxs,
    const float* __restrict__ e2aw, const float* __restrict__ gg, const float* __restrict__ bb,
    const float* __restrict__ mm, const float* __restrict__ vv,
    float* __restrict__ g1, float* __restrict__ out)
{
    const int b  = blockIdx.y;
    const int cg = blockIdx.x >> 2;   // 0..7
    const int rg = blockIdx.x & 3;    // 0..3
    const int t  = threadIdx.x;
    const int row = rg*16 + (t >> 4);
    const int w0  = (t & 15) * 4;

    float c0, c1, c2, cid;
    get_coeffs(wts, idxs, b, c0, c1, c2, cid);
    if (c2 == 0.f) return;

    __shared__ float wlds[8*1152];   // 36 KB
    __shared__ float s_s[8], s_t[8];
    for (int i = t; i < 8*1152; i += 256) {
        int co_l = i / 1152, rest = i % 1152;
        wlds[i] = e2aw[(size_t)(cg*8 + co_l)*1152 + rest];
    }
    if (t < 8) {
        int co = cg*8 + t;
        float s = gg[co] * rsqrtf(vv[co] + 1e-5f);
        s_s[t] = s; s_t[t] = bb[co] - mm[co]*s;
    }
    __syncthreads();

    float acc[8][4];
    #pragma unroll
    for (int i = 0; i < 8; ++i)
        #pragma unroll
        for (int p = 0; p < 4; ++p) acc[i][p] = 0.f;

    const float* xb = x + (size_t)b*C_*HW;
    for (int ci = 0; ci < 128; ++ci) {
        const float* xc = xb + ci*HW;
        #pragma unroll
        for (int dh = 0; dh < 3; ++dh) {
            int hh = row + dh - 1;
            float rbuf[6];
            if (hh >= 0 && hh < H_) {
                const float* xr = xc + hh*W_;
                #pragma unroll
                for (int i = 0; i < 6; ++i) {
                    int wloc = w0 - 1 + i;
                    rbuf[i] = (wloc >= 0 && wloc < W_) ? xr[wloc] : 0.f;
                }
            } else {
                #pragma unroll
                for (int i = 0; i < 6; ++i) rbuf[i] = 0.f;
            }
            #pragma unroll
            for (int co = 0; co < 8; ++co) {
                const float* wp = &wlds[co*1152 + ci*9 + dh*3];
                float wa = wp[0], wb = wp[1], wc = wp[2];
                #pragma unroll
                for (int p = 0; p < 4; ++p)
                    acc[co][p] += rbuf[p]*wa + rbuf[p+1]*wb + rbuf[p+2]*wc;
            }
        }
    }

    #pragma unroll
    for (int i = 0; i < 8; ++i) {
        int co = cg*8 + i;
        float s = s_s[i], tt = s_t[i];
        size_t gbase = ((size_t)(b*CS + co))*HW + row*W_ + w0;
        size_t obase = ((size_t)(b*C_ + co))*HW + row*W_ + w0;
        float4 gv, ov = *(const float4*)(out + obase);
        gv.x = silu_f(acc[i][0]*s + tt);
        gv.y = silu_f(acc[i][1]*s + tt);
        gv.z = silu_f(acc[i][2]*s + tt);
        gv.w = silu_f(acc[i][3]*s + tt);
        *(float4*)(g1 + gbase) = gv;
        ov.x += c2*gv.x; ov.y += c2*gv.y; ov.z += c2*gv.z; ov.w += c2*gv.w;
        *(float4*)(out + obase) = ov;
    }
}

// ---------------- Kernel D: out[:, 64:] += c2 * silu(bn(dwconv5x5(g1))) ---------
// grid (64, B): one (b, channel) plane per block.
__global__ __launch_bounds__(256) void k_e2b(
    const float* __restrict__ g1, const float* __restrict__ wts, const int* __restrict__ idxs,
    const float* __restrict__ dww, const float* __restrict__ gg, const float* __restrict__ bb,
    const float* __restrict__ mm, const float* __restrict__ vv, float* __restrict__ out)
{
    const int b = blockIdx.y;
    const int c = blockIdx.x;   // 0..63
    const int t = threadIdx.x;

    float c0, c1, c2, cid;
    get_coeffs(wts, idxs, b, c0, c1, c2, cid);
    if (c2 == 0.f) return;

    __shared__ float wl[25];
    __shared__ float s_sv, s_tv;
    if (t < 25) wl[t] = dww[c*25 + t];
    if (t == 0) {
        float s = gg[c] * rsqrtf(vv[c] + 1e-5f);
        s_sv = s; s_tv = bb[c] - mm[c]*s;
    }
    __syncthreads();

    const float* gc = g1 + ((size_t)(b*CS + c))*HW;
    float* oc = out + ((size_t)(b*C_ + CS + c))*HW;
    float s = s_sv, tt = s_tv;
    for (int p = t; p < HW; p += 256) {
        int h = p >> 6, w = p & 63;
        float a = 0.f;
        #pragma unroll
        for (int kh = 0; kh < 5; ++kh) {
            int hh = h + kh - 2;
            if (hh < 0 || hh >= H_) continue;
            #pragma unroll
            for (int kw = 0; kw < 5; ++kw) {
                int ww = w + kw - 2;
                if (ww < 0 || ww >= W_) continue;
                a += gc[hh*W_ + ww] * wl[kh*5 + kw];
            }
        }
        oc[p] += c2 * silu_f(a*s + tt);
    }
}

extern "C" void kernel_launch(void* const* d_in, const int* in_sizes, int n_in,
                              void* d_out, int out_size, void* d_ws, size_t ws_size,
                              hipStream_t stream) {
    const float* x    = (const float*)d_in[0];
    const float* wts  = (const float*)d_in[1];
    const int*   idxs = (const int*)  d_in[2];
    const float* e0w  = (const float*)d_in[3];
    const float* e0g  = (const float*)d_in[4];
    const float* e0b  = (const float*)d_in[5];
    const float* e0m  = (const float*)d_in[6];
    const float* e0v  = (const float*)d_in[7];
    const float* e1dw = (const float*)d_in[8];
    const float* e1pw = (const float*)d_in[9];
    const float* e1g  = (const float*)d_in[10];
    const float* e1b  = (const float*)d_in[11];
    const float* e1m  = (const float*)d_in[12];
    const float* e1v  = (const float*)d_in[13];
    const float* e2aw = (const float*)d_in[14];
    const float* e2ag = (const float*)d_in[15];
    const float* e2ab = (const float*)d_in[16];
    const float* e2am = (const float*)d_in[17];
    const float* e2av = (const float*)d_in[18];
    const float* e2bw = (const float*)d_in[19];
    const float* e2bg = (const float*)d_in[20];
    const float* e2bb = (const float*)d_in[21];
    const float* e2bm = (const float*)d_in[22];
    const float* e2bv = (const float*)d_in[23];

    float* out = (float*)d_out;
    float* tmp = (float*)d_ws;                                // 32 MB dw scratch
    float* g1  = (float*)d_ws + (size_t)B_*CS*HW;             // 32 MB g1

    k_e0_id<<<dim3(64, B_), 256, 0, stream>>>(x, wts, idxs, e0w, e0g, e0b, e0m, e0v, out);
    k_e1_dw<<<dim3(CS, B_), 256, 0, stream>>>(x, wts, idxs, e1dw, tmp);
    k_e1_pw<<<dim3(256, B_), 256, 0, stream>>>(tmp, wts, idxs, e1pw, e1g, e1b, e1m, e1v, out);
    k_e2a  <<<dim3(32, B_), 256, 0, stream>>>(x, wts, idxs, e2aw, e2ag, e2ab, e2am, e2av, g1, out);
    k_e2b  <<<dim3(CS, B_), 256, 0, stream>>>(g1, wts, idxs, e2bw, e2bg, e2bb, e2bm, e2bv, out);
}

// Round 2
// 331.468 us; speedup vs baseline: 1.8488x; 1.8488x over previous
//
#include <hip/hip_runtime.h>

#define B_  32
#define C_  128
#define CS  64
#define H_  64
#define W_  64
#define HW  (H_*W_)

typedef __attribute__((ext_vector_type(8))) short bf16x8_t;
typedef __attribute__((ext_vector_type(4))) float f32x4_t;

__device__ __forceinline__ float silu_f(float v) { return v / (1.f + __expf(-v)); }

__device__ __forceinline__ unsigned short f2bf(float f) {
    unsigned int u = __float_as_uint(f);
    u = (u + 0x7FFFu + ((u >> 16) & 1u)) >> 16;   // RNE
    return (unsigned short)u;
}
__device__ __forceinline__ float bf2f(unsigned short u) {
    return __uint_as_float(((unsigned int)u) << 16);
}

__device__ __forceinline__ void get_coeffs(const float* __restrict__ wts,
                                           const int* __restrict__ idxs, int b,
                                           float& c0, float& c1, float& c2, float& cid) {
    int   i0 = idxs[b*2+0], i1 = idxs[b*2+1];
    float w0 = wts[b*2+0],  w1 = wts[b*2+1];
    c0  = (i0==0?w0:0.f)   + (i1==0?w1:0.f);
    c1  = (i0==1?w0:0.f)   + (i1==1?w1:0.f);
    c2  = (i0==2?w0:0.f)   + (i1==2?w1:0.f);
    cid = (i0==3?0.1f:0.f) + (i1==3?0.1f:0.f);
}

// -------- weight transpose+cvt: Wt[tap][co][ci] bf16, from OIHW fp32 ----------
__global__ __launch_bounds__(256) void k_prep_w(
    const float* __restrict__ e0w, const float* __restrict__ e2aw,
    unsigned short* __restrict__ Wt0, unsigned short* __restrict__ Wt2)
{
    const int stride = gridDim.x * 256;
    for (int i = blockIdx.x*256 + threadIdx.x; i < 9*128*64; i += stride) {
        // Wt0: tap, co(128), ci(64)
        int tap = i / (128*64); int rem = i % (128*64); int co = rem / 64; int ci = rem % 64;
        Wt0[i] = f2bf(e0w[(size_t)(co*64 + ci)*9 + tap]);
        // Wt2: tap, co(64), ci(128)
        int tap2 = i / (64*128); int rem2 = i % (64*128); int co2 = rem2 / 128; int ci2 = rem2 % 128;
        Wt2[i] = f2bf(e2aw[(size_t)(co2*128 + ci2)*9 + tap2]);
    }
}

// -------- 3x3 conv + BN + SiLU via bf16 MFMA implicit GEMM --------------------
// MODE 0: e0  (CIN=64,  CPAD=72,  COUT=128): out = c0*e0 + cid*x  (writes ALL of out)
// MODE 1: e2a (CIN=128, CPAD=136, COUT=64) : g1(bf16) = e2a; out[:, :64] += c2*g1
// grid (64 rows, B). block 256 = 4 waves in 2x2 (cout-group x pixel-group).
template<int CIN, int CPAD, int COUT, int MODE>
__global__ __launch_bounds__(256) void k_conv3_mfma(
    const float* __restrict__ x, const float* __restrict__ wts, const int* __restrict__ idxs,
    const unsigned short* __restrict__ Wt,
    const float* __restrict__ gg, const float* __restrict__ bb,
    const float* __restrict__ mm, const float* __restrict__ vv,
    float* __restrict__ out, unsigned short* __restrict__ g1)
{
    const int b = blockIdx.y, orow = blockIdx.x, t = threadIdx.x;

    float c0, c1, c2, cid;
    get_coeffs(wts, idxs, b, c0, c1, c2, cid);

    if (MODE == 0) {
        if (c0 == 0.f) {   // identity-only: still must initialize this row of out
            for (int i = t; i < C_*16; i += 256) {
                int ch = i >> 4, p4 = i & 15;
                size_t base = ((size_t)(b*C_+ch))*HW + orow*64 + p4*4;
                float4 xv = *(const float4*)(x + base);
                float4 o; o.x = cid*xv.x; o.y = cid*xv.y; o.z = cid*xv.z; o.w = cid*xv.w;
                *(float4*)(out + base) = o;
            }
            return;
        }
    } else {
        if (c2 == 0.f) return;
    }

    __shared__ unsigned short lds[3*66*CPAD];

    {   // stage 3 input rows x 66 cols x CIN channels, NHWC bf16
        const int col = t & 63, lc = col + 1, cp = t >> 6;
        const float* xb = x + (size_t)b*C_*HW;
        for (int r = 0; r < 3; ++r) {
            int hh = orow - 1 + r;
            bool inr = (hh >= 0 && hh < H_);
            for (int ci = cp*2; ci < CIN; ci += 8) {
                unsigned int pk = 0u;
                if (inr) {
                    float f0 = xb[(size_t)ci*HW + hh*64 + col];
                    float f1 = xb[(size_t)(ci+1)*HW + hh*64 + col];
                    pk = (unsigned int)f2bf(f0) | ((unsigned int)f2bf(f1) << 16);
                }
                *(unsigned int*)&lds[(r*66 + lc)*CPAD + ci] = pk;
            }
        }
        for (int i = t; i < 3*CPAD; i += 256) {   // zero border cols (w=-1, w=64)
            int r = i / CPAD, j = i % CPAD;
            int side = (j >= CPAD/2);
            int ci = (j - side*(CPAD/2)) * 2;
            *(unsigned int*)&lds[(r*66 + side*65)*CPAD + ci] = 0u;
        }
    }
    __syncthreads();

    const int lane = t & 63, l15 = lane & 15, kg = lane >> 4;
    const int wv = t >> 6, cw = wv >> 1, pw = wv & 1;
    constexpr int NCF = (MODE == 0) ? 4 : 2;   // cout frags per wave
    const int cobase = cw * (NCF*16);
    const int pxbase = pw * 32;

    f32x4_t acc[NCF][2];
    #pragma unroll
    for (int cf = 0; cf < NCF; ++cf)
        #pragma unroll
        for (int pf = 0; pf < 2; ++pf)
            acc[cf][pf] = (f32x4_t){0.f, 0.f, 0.f, 0.f};

    #pragma unroll
    for (int dh = 0; dh < 3; ++dh) {
        #pragma unroll
        for (int dw = 0; dw < 3; ++dw) {
            const unsigned short* wt = Wt + (size_t)(dh*3+dw)*COUT*CIN;
            #pragma unroll
            for (int kc = 0; kc < CIN/32; ++kc) {
                const int k0 = kc*32 + kg*8;
                bf16x8_t af[NCF];
                #pragma unroll
                for (int cf = 0; cf < NCF; ++cf)
                    af[cf] = *(const bf16x8_t*)(wt + (size_t)(cobase + cf*16 + l15)*CIN + k0);
                #pragma unroll
                for (int pf = 0; pf < 2; ++pf) {
                    const bf16x8_t bfr = *(const bf16x8_t*)(&lds[(dh*66 + pxbase + pf*16 + l15 + dw)*CPAD + k0]);
                    #pragma unroll
                    for (int cf = 0; cf < NCF; ++cf)
                        acc[cf][pf] = __builtin_amdgcn_mfma_f32_16x16x32_bf16(af[cf], bfr, acc[cf][pf], 0, 0, 0);
                }
            }
        }
    }

    // epilogue: D col=lane&15 = pixel, row=(lane>>4)*4+reg = cout (m89-verified)
    #pragma unroll
    for (int cf = 0; cf < NCF; ++cf) {
        float sarr[4], tarr[4];
        #pragma unroll
        for (int r = 0; r < 4; ++r) {
            int co = cobase + cf*16 + kg*4 + r;
            float s = gg[co] * rsqrtf(vv[co] + 1e-5f);
            sarr[r] = s; tarr[r] = bb[co] - mm[co]*s;
        }
        #pragma unroll
        for (int pf = 0; pf < 2; ++pf) {
            #pragma unroll
            for (int r = 0; r < 4; ++r) {
                int co = cobase + cf*16 + kg*4 + r;
                int px = pxbase + pf*16 + l15;
                float v = silu_f(acc[cf][pf][r]*sarr[r] + tarr[r]);
                if (MODE == 0) {
                    size_t o = ((size_t)(b*C_+co))*HW + orow*64 + px;
                    out[o] = c0*v + cid*x[o];
                } else {
                    size_t go = ((size_t)(b*CS+co))*HW + orow*64 + px;
                    size_t o  = ((size_t)(b*C_+co))*HW + orow*64 + px;
                    g1[go] = f2bf(v);
                    out[o] += c2*v;
                }
            }
        }
    }
}

// ---------------- e1 depthwise 5x5 (bf16 tmp out) -----------------------------
__global__ __launch_bounds__(256) void k_e1_dw(
    const float* __restrict__ x, const float* __restrict__ wts, const int* __restrict__ idxs,
    const float* __restrict__ dww, unsigned short* __restrict__ tmp)
{
    const int b = blockIdx.y;
    const int c = blockIdx.x;
    const int t = threadIdx.x;

    float c0, c1, c2, cid;
    get_coeffs(wts, idxs, b, c0, c1, c2, cid);
    if (c1 == 0.f) return;

    __shared__ float wl[25];
    if (t < 25) wl[t] = dww[c*25 + t];
    __syncthreads();

    const float* xc = x + ((size_t)(b*C_ + CS + c))*HW;
    unsigned short* tc = tmp + ((size_t)(b*CS + c))*HW;
    for (int p = t; p < HW; p += 256) {
        int h = p >> 6, w = p & 63;
        float a = 0.f;
        #pragma unroll
        for (int kh = 0; kh < 5; ++kh) {
            int hh = h + kh - 2;
            if (hh < 0 || hh >= H_) continue;
            #pragma unroll
            for (int kw = 0; kw < 5; ++kw) {
                int ww = w + kw - 2;
                if (ww < 0 || ww >= W_) continue;
                a += xc[hh*W_ + ww] * wl[kh*5 + kw];
            }
        }
        tc[p] = f2bf(a);
    }
}

// ---------------- e1 pointwise 1x1 + BN + SiLU: out += c1 * e1 ----------------
__global__ __launch_bounds__(256) void k_e1_pw(
    const unsigned short* __restrict__ tmp, const float* __restrict__ wts, const int* __restrict__ idxs,
    const float* __restrict__ pww, const float* __restrict__ gg, const float* __restrict__ bb,
    const float* __restrict__ mm, const float* __restrict__ vv, float* __restrict__ out)
{
    const int b  = blockIdx.y;
    const int cg = blockIdx.x >> 4;
    const int pc = blockIdx.x & 15;
    const int t  = threadIdx.x;

    float c0, c1, c2, cid;
    get_coeffs(wts, idxs, b, c0, c1, c2, cid);
    if (c1 == 0.f) return;

    __shared__ float wl[8*64];
    __shared__ float s_s[8], s_t[8];
    for (int i = t; i < 8*64; i += 256) {
        int co_l = i >> 6, ci = i & 63;
        wl[i] = pww[(size_t)(cg*8 + co_l)*64 + ci];
    }
    if (t < 8) {
        int co = cg*8 + t;
        float s = gg[co] * rsqrtf(vv[co] + 1e-5f);
        s_s[t] = s; s_t[t] = bb[co] - mm[co]*s;
    }
    __syncthreads();

    const int pix = pc*256 + t;
    const unsigned short* tb = tmp + (size_t)b*CS*HW + pix;
    float acc[8];
    #pragma unroll
    for (int i = 0; i < 8; ++i) acc[i] = 0.f;

    for (int ci = 0; ci < 64; ++ci) {
        float tv = bf2f(tb[(size_t)ci*HW]);
        #pragma unroll
        for (int co = 0; co < 8; ++co) acc[co] += tv * wl[co*64 + ci];
    }

    #pragma unroll
    for (int i = 0; i < 8; ++i) {
        int co = cg*8 + i;
        size_t o = ((size_t)(b*C_ + co))*HW + pix;
        float val = silu_f(acc[i]*s_s[i] + s_t[i]);
        out[o] += c1 * val;
    }
}

// ---------------- e2b depthwise 5x5 + BN + SiLU: out[:, 64:] += c2*g2 ---------
__global__ __launch_bounds__(256) void k_e2b(
    const unsigned short* __restrict__ g1, const float* __restrict__ wts, const int* __restrict__ idxs,
    const float* __restrict__ dww, const float* __restrict__ gg, const float* __restrict__ bb,
    const float* __restrict__ mm, const float* __restrict__ vv, float* __restrict__ out)
{
    const int b = blockIdx.y;
    const int c = blockIdx.x;
    const int t = threadIdx.x;

    float c0, c1, c2, cid;
    get_coeffs(wts, idxs, b, c0, c1, c2, cid);
    if (c2 == 0.f) return;

    __shared__ float wl[25];
    __shared__ float s_sv, s_tv;
    if (t < 25) wl[t] = dww[c*25 + t];
    if (t == 0) {
        float s = gg[c] * rsqrtf(vv[c] + 1e-5f);
        s_sv = s; s_tv = bb[c] - mm[c]*s;
    }
    __syncthreads();

    const unsigned short* gc = g1 + ((size_t)(b*CS + c))*HW;
    float* oc = out + ((size_t)(b*C_ + CS + c))*HW;
    float s = s_sv, tt = s_tv;
    for (int p = t; p < HW; p += 256) {
        int h = p >> 6, w = p & 63;
        float a = 0.f;
        #pragma unroll
        for (int kh = 0; kh < 5; ++kh) {
            int hh = h + kh - 2;
            if (hh < 0 || hh >= H_) continue;
            #pragma unroll
            for (int kw = 0; kw < 5; ++kw) {
                int ww = w + kw - 2;
                if (ww < 0 || ww >= W_) continue;
                a += bf2f(gc[hh*W_ + ww]) * wl[kh*5 + kw];
            }
        }
        oc[p] += c2 * silu_f(a*s + tt);
    }
}

extern "C" void kernel_launch(void* const* d_in, const int* in_sizes, int n_in,
                              void* d_out, int out_size, void* d_ws, size_t ws_size,
                              hipStream_t stream) {
    const float* x    = (const float*)d_in[0];
    const float* wts  = (const float*)d_in[1];
    const int*   idxs = (const int*)  d_in[2];
    const float* e0w  = (const float*)d_in[3];
    const float* e0g  = (const float*)d_in[4];
    const float* e0b  = (const float*)d_in[5];
    const float* e0m  = (const float*)d_in[6];
    const float* e0v  = (const float*)d_in[7];
    const float* e1dw = (const float*)d_in[8];
    const float* e1pw = (const float*)d_in[9];
    const float* e1g  = (const float*)d_in[10];
    const float* e1b  = (const float*)d_in[11];
    const float* e1m  = (const float*)d_in[12];
    const float* e1v  = (const float*)d_in[13];
    const float* e2aw = (const float*)d_in[14];
    const float* e2ag = (const float*)d_in[15];
    const float* e2ab = (const float*)d_in[16];
    const float* e2am = (const float*)d_in[17];
    const float* e2av = (const float*)d_in[18];
    const float* e2bw = (const float*)d_in[19];
    const float* e2bg = (const float*)d_in[20];
    const float* e2bb = (const float*)d_in[21];
    const float* e2bm = (const float*)d_in[22];
    const float* e2bv = (const float*)d_in[23];

    float* out = (float*)d_out;

    unsigned short* Wt0 = (unsigned short*)d_ws;            // 9*128*64 bf16
    unsigned short* Wt2 = Wt0 + 9*128*64;                   // 9*64*128 bf16
    unsigned short* tmp = Wt2 + 9*64*128;                   // B*CS*HW bf16 (16 MB)
    unsigned short* g1  = tmp + (size_t)B_*CS*HW;           // B*CS*HW bf16 (16 MB)

    k_prep_w<<<288, 256, 0, stream>>>(e0w, e2aw, Wt0, Wt2);
    k_conv3_mfma<64, 72, 128, 0><<<dim3(64, B_), 256, 0, stream>>>(
        x, wts, idxs, Wt0, e0g, e0b, e0m, e0v, out, nullptr);
    k_e1_dw<<<dim3(CS, B_), 256, 0, stream>>>(x, wts, idxs, e1dw, tmp);
    k_e1_pw<<<dim3(256, B_), 256, 0, stream>>>(tmp, wts, idxs, e1pw, e1g, e1b, e1m, e1v, out);
    k_conv3_mfma<128, 136, 64, 1><<<dim3(64, B_), 256, 0, stream>>>(
        x, wts, idxs, Wt2, e2ag, e2ab, e2am, e2av, out, g1);
    k_e2b<<<dim3(CS, B_), 256, 0, stream>>>(g1, wts, idxs, e2bw, e2bg, e2bb, e2bm, e2bv, out);
}

// Round 3
// 137.745 us; speedup vs baseline: 4.4490x; 2.4064x over previous
//
#include <hip/hip_runtime.h>

#define B_  32
#define C_  128
#define CS  64
#define H_  64
#define W_  64
#define HW  (H_*W_)

typedef __attribute__((ext_vector_type(8))) short bf16x8_t;
typedef __attribute__((ext_vector_type(4))) float f32x4_t;
typedef unsigned short u16;
typedef unsigned int   u32;

__device__ __forceinline__ float silu_f(float v) { return v / (1.f + __expf(-v)); }

__device__ __forceinline__ u16 f2bf(float f) {
    u32 u = __float_as_uint(f);
    u = (u + 0x7FFFu + ((u >> 16) & 1u)) >> 16;   // RNE
    return (u16)u;
}
__device__ __forceinline__ float bf2f(u16 u) {
    return __uint_as_float(((u32)u) << 16);
}
__device__ __forceinline__ u32 pack2(float a, float b) {
    return (u32)f2bf(a) | ((u32)f2bf(b) << 16);
}

__device__ __forceinline__ void get_coeffs(const float* __restrict__ wts,
                                           const int* __restrict__ idxs, int b,
                                           float& c0, float& c1, float& c2, float& cid) {
    int   i0 = idxs[b*2+0], i1 = idxs[b*2+1];
    float w0 = wts[b*2+0],  w1 = wts[b*2+1];
    c0  = (i0==0?w0:0.f)   + (i1==0?w1:0.f);
    c1  = (i0==1?w0:0.f)   + (i1==1?w1:0.f);
    c2  = (i0==2?w0:0.f)   + (i1==2?w1:0.f);
    cid = (i0==3?0.1f:0.f) + (i1==3?0.1f:0.f);
}

// ---- weight prep: MFMA-fragment-ordered bf16 weights --------------------------
// Wt0f: e0  [tap9][kc2][cog8][lane64][8]   A[row=co=cog*16+(l&15)][k=kc*32+(l>>4)*8+j]
// Wt2f: e2a [tap9][kc4][cog4][lane64][8]
// Wt1f: e1pw[kc2][cog8][lane64][8]
__global__ __launch_bounds__(256) void k_prep(
    const float* __restrict__ e0w, const float* __restrict__ e2aw, const float* __restrict__ e1pw,
    u16* __restrict__ Wt0f, u16* __restrict__ Wt2f, u16* __restrict__ Wt1f)
{
    const int i0 = blockIdx.x*256 + threadIdx.x, stride = gridDim.x*256;
    for (int i = i0; i < 73728; i += stride) {
        int j = i&7, lane = (i>>3)&63, cog = (i>>9)&7, kc = (i>>12)&1, tap = i>>13;
        int co = cog*16 + (lane&15), ci = kc*32 + (lane>>4)*8 + j;
        Wt0f[i] = f2bf(e0w[(size_t)(co*64 + ci)*9 + tap]);
    }
    for (int i = i0; i < 73728; i += stride) {
        int j = i&7, lane = (i>>3)&63, cog = (i>>9)&3, kc = (i>>11)&3, tap = i>>13;
        int co = cog*16 + (lane&15), ci = kc*32 + (lane>>4)*8 + j;
        Wt2f[i] = f2bf(e2aw[(size_t)(co*128 + ci)*9 + tap]);
    }
    for (int i = i0; i < 8192; i += stride) {
        int j = i&7, lane = (i>>3)&63, cog = (i>>9)&7, kc = (i>>12)&1;
        int co = cog*16 + (lane&15), ci = kc*32 + (lane>>4)*8 + j;
        Wt1f[i] = f2bf(e1pw[(size_t)co*64 + ci]);
    }
}

// ---- NCHW fp32 -> NHWC bf16 (per (b,h) row, LDS transpose) --------------------
__global__ __launch_bounds__(256) void k_to_nhwc(
    const float* __restrict__ x, const float* __restrict__ wts, const int* __restrict__ idxs,
    u16* __restrict__ xh)
{
    const int b = blockIdx.y, h = blockIdx.x, t = threadIdx.x;
    float c0, c1, c2, cid;
    get_coeffs(wts, idxs, b, c0, c1, c2, cid);
    if (c0 == 0.f && c2 == 0.f) return;
    const int chmax = (c2 != 0.f) ? 128 : 64;

    __shared__ float ld[128*66];
    for (int i = t; i < chmax*16; i += 256) {
        int ch = i >> 4, q = i & 15;
        float4 v = *(const float4*)(x + ((size_t)(b*C_+ch))*HW + h*64 + q*4);
        float* p = &ld[ch*66 + q*4];
        p[0] = v.x; p[1] = v.y; p[2] = v.z; p[3] = v.w;
    }
    __syncthreads();

    const int px = t >> 2, sub = t & 3;
    u16* rec = xh + (((size_t)b*64 + h)*64 + px)*C_;
    for (int c = sub; c < chmax/8; c += 4) {
        uint4 v;
        u32 w[4];
        #pragma unroll
        for (int k = 0; k < 4; ++k)
            w[k] = pack2(ld[(c*8 + 2*k)*66 + px], ld[(c*8 + 2*k + 1)*66 + px]);
        v.x = w[0]; v.y = w[1]; v.z = w[2]; v.w = w[3];
        *(uint4*)(rec + c*8) = v;
    }
}

// ---- 3x3 conv + BN + SiLU via bf16 MFMA, 2 output rows per block --------------
// MODE 0: e0  (CIN=64, COUT=128): out = c0*e0 + cid*x  (writes everything)
// MODE 1: e2a (CIN=128, COUT=64): g1 = e2a (bf16); out[:, :64] += c2*g1
template<int CIN, int CPAD, int COUT, int MODE>
__global__ __launch_bounds__(256) void k_conv3(
    const u16* __restrict__ xh, const float* __restrict__ x,
    const float* __restrict__ wts, const int* __restrict__ idxs,
    const u16* __restrict__ Wtf,
    const float* __restrict__ gg, const float* __restrict__ bb,
    const float* __restrict__ mm, const float* __restrict__ vv,
    float* __restrict__ out, u16* __restrict__ g1)
{
    const int b = blockIdx.y, band = blockIdx.x, t = threadIdx.x;
    const int orow0 = band*2;

    float c0, c1, c2, cid;
    get_coeffs(wts, idxs, b, c0, c1, c2, cid);

    if (MODE == 0) {
        if (c0 == 0.f) {   // identity-only: initialize these 2 rows of out
            for (int i = t; i < C_*32; i += 256) {
                int ch = i >> 5, r = (i >> 4) & 1, q = i & 15;
                size_t o = ((size_t)(b*C_+ch))*HW + (size_t)(orow0+r)*64 + q*4;
                float4 ov;
                if (cid != 0.f) {
                    float4 xv = *(const float4*)(x + o);
                    ov.x = cid*xv.x; ov.y = cid*xv.y; ov.z = cid*xv.z; ov.w = cid*xv.w;
                } else { ov.x = ov.y = ov.z = ov.w = 0.f; }
                *(float4*)(out + o) = ov;
            }
            return;
        }
    } else {
        if (c2 == 0.f) return;
    }

    constexpr int NCH = CIN/8, KC = CIN/32;
    __shared__ u16 lds[4*66*CPAD];

    for (int i = t; i < 4*64*NCH; i += 256) {
        int cg = i % NCH, col = (i/NCH) & 63, r = i/(NCH*64);
        int hh = orow0 - 1 + r;
        uint4 v; v.x = v.y = v.z = v.w = 0u;
        if (hh >= 0 && hh < H_)
            v = *(const uint4*)(xh + (((size_t)b*64 + hh)*64 + col)*C_ + cg*8);
        *(uint4*)&lds[(r*66 + col + 1)*CPAD + cg*8] = v;
    }
    for (int i = t; i < 4*2*NCH; i += 256) {
        int cg = i % NCH, side = (i/NCH) & 1, r = i/(NCH*2);
        uint4 z; z.x = z.y = z.z = z.w = 0u;
        *(uint4*)&lds[(r*66 + side*65)*CPAD + cg*8] = z;
    }
    __syncthreads();

    const int lane = t & 63, l15 = lane & 15, kg = lane >> 4;
    const int wv = t >> 6, cw = wv >> 1, pw = wv & 1;
    constexpr int NCF = (MODE == 0) ? 4 : 2;
    const int cobase = cw * (NCF*16);
    const int pxbase = pw * 64;

    f32x4_t acc[NCF][4];
    #pragma unroll
    for (int cf = 0; cf < NCF; ++cf)
        #pragma unroll
        for (int pf = 0; pf < 4; ++pf)
            acc[cf][pf] = (f32x4_t){0.f, 0.f, 0.f, 0.f};

    #pragma unroll
    for (int tap = 0; tap < 9; ++tap) {
        const int dh = tap/3, dwp = tap%3;
        #pragma unroll
        for (int kc = 0; kc < KC; ++kc) {
            const u16* wt = Wtf + (((size_t)((tap*KC + kc)*(COUT/16) + (cobase>>4))) << 9) + lane*8;
            bf16x8_t af[NCF];
            #pragma unroll
            for (int cf = 0; cf < NCF; ++cf)
                af[cf] = *(const bf16x8_t*)(wt + (cf << 9));
            const int k0 = kc*32 + kg*8;
            #pragma unroll
            for (int pf = 0; pf < 4; ++pf) {
                const int P = pxbase + pf*16;
                bf16x8_t bfr = *(const bf16x8_t*)&lds[(((P>>6) + dh)*66 + (P&63) + l15 + dwp)*CPAD + k0];
                #pragma unroll
                for (int cf = 0; cf < NCF; ++cf)
                    acc[cf][pf] = __builtin_amdgcn_mfma_f32_16x16x32_bf16(af[cf], bfr, acc[cf][pf], 0, 0, 0);
            }
        }
    }

    // D: col=lane&15=pixel, row=(lane>>4)*4+reg=cout
    #pragma unroll
    for (int cf = 0; cf < NCF; ++cf) {
        float sarr[4], tarr[4];
        #pragma unroll
        for (int r = 0; r < 4; ++r) {
            int co = cobase + cf*16 + kg*4 + r;
            float s = gg[co] * rsqrtf(vv[co] + 1e-5f);
            sarr[r] = s; tarr[r] = bb[co] - mm[co]*s;
        }
        #pragma unroll
        for (int pf = 0; pf < 4; ++pf) {
            int px = pxbase + pf*16 + l15;
            size_t rowoff = (size_t)(orow0 + (px>>6))*64 + (px&63);
            #pragma unroll
            for (int r = 0; r < 4; ++r) {
                int co = cobase + cf*16 + kg*4 + r;
                float v = silu_f(acc[cf][pf][r]*sarr[r] + tarr[r]);
                if (MODE == 0) {
                    size_t o = ((size_t)(b*C_+co))*HW + rowoff;
                    float idv = (cid != 0.f) ? cid*x[o] : 0.f;
                    out[o] = c0*v + idv;
                } else {
                    g1[((size_t)(b*CS+co))*HW + rowoff] = f2bf(v);
                    out[((size_t)(b*C_+co))*HW + rowoff] += c2*v;
                }
            }
        }
    }
}

// ---- fused e1: dw5x5(x_ir) in LDS -> pw1x1 MFMA -> BN/SiLU -> out += c1*e1 ----
// block = (band of 2 rows, b). 4 waves: dw phase (outrow x chhalf), pw phase (cw x pw).
__global__ __launch_bounds__(256) void k_e1(
    const float* __restrict__ x, const float* __restrict__ wts, const int* __restrict__ idxs,
    const float* __restrict__ dww, const u16* __restrict__ Wt1f,
    const float* __restrict__ gg, const float* __restrict__ bb,
    const float* __restrict__ mm, const float* __restrict__ vv,
    float* __restrict__ out)
{
    const int b = blockIdx.y, band = blockIdx.x, t = threadIdx.x;
    const int orow0 = band*2;

    float c0, c1, c2, cid;
    get_coeffs(wts, idxs, b, c0, c1, c2, cid);
    if (c1 == 0.f) return;

    __shared__ u16  lin[6*64*70];   // [row6][ch64][col70] cols -2..65 (+pad), bf16
    __shared__ u16  lout[128*72];   // [px128][ci72pad] bf16
    __shared__ float wl[64*26];

    for (int i = t; i < 64*25; i += 256) wl[(i/25)*26 + (i%25)] = dww[i];
    for (int i = t; i < 6*64*16; i += 256) {
        int q = i & 15, ch = (i >> 4) & 63, r = i >> 10;
        int hh = orow0 - 2 + r;
        u32 w0 = 0u, w1 = 0u;
        if (hh >= 0 && hh < H_) {
            float4 v = *(const float4*)(x + ((size_t)(b*C_ + CS + ch))*HW + hh*64 + q*4);
            w0 = pack2(v.x, v.y); w1 = pack2(v.z, v.w);
        }
        u32* dst = (u32*)&lin[(r*64 + ch)*70 + 2 + q*4];
        dst[0] = w0; dst[1] = w1;
    }
    for (int i = t; i < 6*64; i += 256) {
        int ch = i & 63, r = i >> 6;
        *(u32*)&lin[(r*64 + ch)*70]      = 0u;   // cols 0,1
        u32* e = (u32*)&lin[(r*64 + ch)*70 + 66];
        e[0] = 0u; e[1] = 0u;                    // cols 66..69
    }
    __syncthreads();

    const int lane = t & 63, chl = lane & 15, cs = lane >> 4;
    const int wv = t >> 6, outrow = wv & 1, chhalf = wv >> 1;

    #pragma unroll
    for (int chi = 0; chi < 2; ++chi) {
        const int ch = chhalf*32 + chl + chi*16;
        const float* wch = &wl[ch*26];
        float accp[16];
        #pragma unroll
        for (int p = 0; p < 16; ++p) accp[p] = 0.f;
        #pragma unroll
        for (int kh = 0; kh < 5; ++kh) {
            const u16* src = &lin[((outrow + kh)*64 + ch)*70 + cs*16];
            float rb[20];
            #pragma unroll
            for (int k = 0; k < 10; ++k) {
                u32 u = *(const u32*)(src + 2*k);
                rb[2*k]   = __uint_as_float(u << 16);
                rb[2*k+1] = __uint_as_float(u & 0xFFFF0000u);
            }
            #pragma unroll
            for (int kw = 0; kw < 5; ++kw) {
                float wvv = wch[kh*5 + kw];
                #pragma unroll
                for (int p = 0; p < 16; ++p) accp[p] += rb[p+kw]*wvv;
            }
        }
        const int px0 = outrow*64 + cs*16;
        #pragma unroll
        for (int p = 0; p < 16; ++p) lout[(px0+p)*72 + ch] = f2bf(accp[p]);
    }
    __syncthreads();

    // pw MFMA: 128 co x 128 px, K=64
    const int l15 = lane & 15, kg = lane >> 4;
    const int cw = wv >> 1, pwv = wv & 1;
    f32x4_t acc[4][4];
    #pragma unroll
    for (int cf = 0; cf < 4; ++cf)
        #pragma unroll
        for (int pf = 0; pf < 4; ++pf)
            acc[cf][pf] = (f32x4_t){0.f, 0.f, 0.f, 0.f};

    #pragma unroll
    for (int kc = 0; kc < 2; ++kc) {
        const u16* wt = Wt1f + (((size_t)(kc*8 + cw*4)) << 9) + lane*8;
        bf16x8_t af[4];
        #pragma unroll
        for (int cf = 0; cf < 4; ++cf) af[cf] = *(const bf16x8_t*)(wt + (cf << 9));
        const int k0 = kc*32 + kg*8;
        #pragma unroll
        for (int pf = 0; pf < 4; ++pf) {
            bf16x8_t bfr = *(const bf16x8_t*)&lout[(pwv*64 + pf*16 + l15)*72 + k0];
            #pragma unroll
            for (int cf = 0; cf < 4; ++cf)
                acc[cf][pf] = __builtin_amdgcn_mfma_f32_16x16x32_bf16(af[cf], bfr, acc[cf][pf], 0, 0, 0);
        }
    }

    #pragma unroll
    for (int cf = 0; cf < 4; ++cf) {
        float sarr[4], tarr[4];
        #pragma unroll
        for (int r = 0; r < 4; ++r) {
            int co = cw*64 + cf*16 + kg*4 + r;
            float s = gg[co] * rsqrtf(vv[co] + 1e-5f);
            sarr[r] = s; tarr[r] = bb[co] - mm[co]*s;
        }
        #pragma unroll
        for (int pf = 0; pf < 4; ++pf) {
            int px = pwv*64 + pf*16 + l15;
            size_t rowoff = (size_t)(orow0 + (px>>6))*64 + (px&63);
            #pragma unroll
            for (int r = 0; r < 4; ++r) {
                int co = cw*64 + cf*16 + kg*4 + r;
                float v = silu_f(acc[cf][pf][r]*sarr[r] + tarr[r]);
                out[((size_t)(b*C_+co))*HW + rowoff] += c1*v;
            }
        }
    }
}

// ---- e2b: dw5x5(g1) + BN + SiLU, out[:, 64:] += c2*g2 (band kernel) -----------
__global__ __launch_bounds__(256) void k_e2b(
    const u16* __restrict__ g1, const float* __restrict__ wts, const int* __restrict__ idxs,
    const float* __restrict__ dww, const float* __restrict__ gg, const float* __restrict__ bb,
    const float* __restrict__ mm, const float* __restrict__ vv, float* __restrict__ out)
{
    const int b = blockIdx.y, band = blockIdx.x, t = threadIdx.x;
    const int orow0 = band*2;

    float c0, c1, c2, cid;
    get_coeffs(wts, idxs, b, c0, c1, c2, cid);
    if (c2 == 0.f) return;

    __shared__ u16  lin[6*64*70];
    __shared__ float wl[64*26];

    for (int i = t; i < 64*25; i += 256) wl[(i/25)*26 + (i%25)] = dww[i];
    for (int i = t; i < 6*64*16; i += 256) {
        int q = i & 15, ch = (i >> 4) & 63, r = i >> 10;
        int hh = orow0 - 2 + r;
        u32 w0 = 0u, w1 = 0u;
        if (hh >= 0 && hh < H_) {
            const u32* src = (const u32*)(g1 + ((size_t)(b*CS+ch))*HW + hh*64 + q*4);
            w0 = src[0]; w1 = src[1];
        }
        u32* dst = (u32*)&lin[(r*64 + ch)*70 + 2 + q*4];
        dst[0] = w0; dst[1] = w1;
    }
    for (int i = t; i < 6*64; i += 256) {
        int ch = i & 63, r = i >> 6;
        *(u32*)&lin[(r*64 + ch)*70] = 0u;
        u32* e = (u32*)&lin[(r*64 + ch)*70 + 66];
        e[0] = 0u; e[1] = 0u;
    }
    __syncthreads();

    const int lane = t & 63, chl = lane & 15, cs = lane >> 4;
    const int wv = t >> 6, outrow = wv & 1, chhalf = wv >> 1;

    #pragma unroll
    for (int chi = 0; chi < 2; ++chi) {
        const int ch = chhalf*32 + chl + chi*16;
        const float* wch = &wl[ch*26];
        float accp[16];
        #pragma unroll
        for (int p = 0; p < 16; ++p) accp[p] = 0.f;
        #pragma unroll
        for (int kh = 0; kh < 5; ++kh) {
            const u16* src = &lin[((outrow + kh)*64 + ch)*70 + cs*16];
            float rb[20];
            #pragma unroll
            for (int k = 0; k < 10; ++k) {
                u32 u = *(const u32*)(src + 2*k);
                rb[2*k]   = __uint_as_float(u << 16);
                rb[2*k+1] = __uint_as_float(u & 0xFFFF0000u);
            }
            #pragma unroll
            for (int kw = 0; kw < 5; ++kw) {
                float wvv = wch[kh*5 + kw];
                #pragma unroll
                for (int p = 0; p < 16; ++p) accp[p] += rb[p+kw]*wvv;
            }
        }
        float s = gg[ch] * rsqrtf(vv[ch] + 1e-5f);
        float tt = bb[ch] - mm[ch]*s;
        float* op = out + ((size_t)(b*C_ + CS + ch))*HW + (size_t)(orow0+outrow)*64 + cs*16;
        #pragma unroll
        for (int q = 0; q < 4; ++q) {
            float4 ov = *(float4*)(op + q*4);
            ov.x += c2*silu_f(accp[q*4+0]*s + tt);
            ov.y += c2*silu_f(accp[q*4+1]*s + tt);
            ov.z += c2*silu_f(accp[q*4+2]*s + tt);
            ov.w += c2*silu_f(accp[q*4+3]*s + tt);
            *(float4*)(op + q*4) = ov;
        }
    }
}

extern "C" void kernel_launch(void* const* d_in, const int* in_sizes, int n_in,
                              void* d_out, int out_size, void* d_ws, size_t ws_size,
                              hipStream_t stream) {
    const float* x    = (const float*)d_in[0];
    const float* wts  = (const float*)d_in[1];
    const int*   idxs = (const int*)  d_in[2];
    const float* e0w  = (const float*)d_in[3];
    const float* e0g  = (const float*)d_in[4];
    const float* e0b  = (const float*)d_in[5];
    const float* e0m  = (const float*)d_in[6];
    const float* e0v  = (const float*)d_in[7];
    const float* e1dw = (const float*)d_in[8];
    const float* e1pw = (const float*)d_in[9];
    const float* e1g  = (const float*)d_in[10];
    const float* e1b  = (const float*)d_in[11];
    const float* e1m  = (const float*)d_in[12];
    const float* e1v  = (const float*)d_in[13];
    const float* e2aw = (const float*)d_in[14];
    const float* e2ag = (const float*)d_in[15];
    const float* e2ab = (const float*)d_in[16];
    const float* e2am = (const float*)d_in[17];
    const float* e2av = (const float*)d_in[18];
    const float* e2bw = (const float*)d_in[19];
    const float* e2bg = (const float*)d_in[20];
    const float* e2bb = (const float*)d_in[21];
    const float* e2bm = (const float*)d_in[22];
    const float* e2bv = (const float*)d_in[23];

    float* out = (float*)d_out;

    u16* xh   = (u16*)d_ws;                    // [b][h][w][128] bf16, 33.5 MB
    u16* g1   = xh + (size_t)16777216;         // [b][64][HW] bf16, 16.8 MB
    u16* Wt0f = g1 + (size_t)8388608;          // 73728
    u16* Wt2f = Wt0f + 73728;                  // 73728
    u16* Wt1f = Wt2f + 73728;                  // 8192

    k_prep<<<128, 256, 0, stream>>>(e0w, e2aw, e1pw, Wt0f, Wt2f, Wt1f);
    k_to_nhwc<<<dim3(64, B_), 256, 0, stream>>>(x, wts, idxs, xh);
    k_conv3<64, 72, 128, 0><<<dim3(32, B_), 256, 0, stream>>>(
        xh, x, wts, idxs, Wt0f, e0g, e0b, e0m, e0v, out, nullptr);
    k_e1<<<dim3(32, B_), 256, 0, stream>>>(
        x, wts, idxs, e1dw, Wt1f, e1g, e1b, e1m, e1v, out);
    k_conv3<128, 136, 64, 1><<<dim3(32, B_), 256, 0, stream>>>(
        xh, x, wts, idxs, Wt2f, e2ag, e2ab, e2am, e2av, out, g1);
    k_e2b<<<dim3(32, B_), 256, 0, stream>>>(
        g1, wts, idxs, e2bw, e2bg, e2bb, e2bm, e2bv, out);
}